// Round 1
// baseline (271.476 us; speedup 1.0000x reference)
//
#include <hip/hip_runtime.h>

#define BM 256          // rows per block = 64 images x 4 patches
#define BN 112          // output cols per chunk (7 chunks of 112 = 784)
#define KP 200          // LDS row stride in bf16 elements (196 real + 4 zero pad)
#define NCH 7

typedef float f32x4 __attribute__((ext_vector_type(4)));
typedef short s16x8 __attribute__((ext_vector_type(8)));

__device__ __forceinline__ unsigned short f2bf(float f) {
    unsigned int u = __builtin_bit_cast(unsigned int, f);
    u += 0x7fffu + ((u >> 16) & 1u);          // round-to-nearest-even
    return (unsigned short)(u >> 16);
}

__global__ __launch_bounds__(256, 1)
void patch_linear_mfma(const float* __restrict__ x,
                       const float* __restrict__ Wlin,
                       const float* __restrict__ blin,
                       float* __restrict__ out) {
    // 102400 + 44800 = 147200 B LDS (< 160 KiB)
    __shared__ __align__(16) short sA[BM * KP];
    __shared__ __align__(16) short sW[BN * KP];

    const int tid  = threadIdx.x;
    const int l    = tid & 63;
    const int wv   = tid >> 6;          // wave 0..3
    const int lrow = l & 15;
    const int lko  = (l >> 4) * 16;     // byte offset of this lane's k-slice

    // ---------------- stage A once: 64 images -> patch-layout bf16 ----------------
    // x rows are fully coalesced float4 reads; scatter into LDS as bf16 pairs.
    const float* xb = x + (size_t)blockIdx.x * (BM / 4) * 784;
    const f32x4* xv = (const f32x4*)xb;
    for (int v = tid; v < (BM / 4) * 784 / 4; v += 256) {   // 12544 vectors
        f32x4 d = xv[v];
        int F   = v * 4;
        int img = F / 784;
        int rem = F - img * 784;
        int h   = rem / 28;
        int w0  = rem - h * 28;          // in {0,4,...,24}
        int ph  = h / 14;
        int r   = h - ph * 14;
        int rowb = img * 4 + ph * 2;
        #pragma unroll
        for (int p = 0; p < 2; ++p) {
            int w  = w0 + 2 * p;         // even => a bf16 pair never straddles a patch
            int pw = (w >= 14) ? 1 : 0;
            int c  = w - pw * 14;
            int row = rowb + pw;
            unsigned int pack = (unsigned int)f2bf(d[2 * p]) |
                                ((unsigned int)f2bf(d[2 * p + 1]) << 16);
            *(unsigned int*)((char*)sA + row * (KP * 2) + (r * 14 + c) * 2) = pack;
        }
    }
    // zero pad k = 196..199 for every A row (8B store, aligned: 400*row+392)
    if (tid < BM) {
        *(unsigned long long*)((char*)sA + tid * (KP * 2) + 392) = 0ull;
    }

    const size_t outRowBase = (size_t)blockIdx.x * BM;

    for (int ch = 0; ch < NCH; ++ch) {
        __syncthreads();   // A ready (first iter) / previous compute done with sW

        // ---------------- stage W chunk (fp32 from L2 -> bf16 LDS) ----------------
        const float* wc = Wlin + (size_t)ch * BN * 196;
        const f32x4* wp = (const f32x4*)wc;
        for (int v = tid; v < BN * 196 / 4; v += 256) {     // 5488 vectors
            f32x4 d = wp[v];
            int F = v * 4;
            int n = F / 196;
            int k = F - n * 196;                            // multiple of 4
            uint2 pk;
            pk.x = (unsigned int)f2bf(d[0]) | ((unsigned int)f2bf(d[1]) << 16);
            pk.y = (unsigned int)f2bf(d[2]) | ((unsigned int)f2bf(d[3]) << 16);
            *(uint2*)((char*)sW + n * (KP * 2) + k * 2) = pk;
        }
        if (tid < BN) {
            *(unsigned long long*)((char*)sW + tid * (KP * 2) + 392) = 0ull;
        }
        __syncthreads();

        const int nbase = ch * BN;
        float bias_r[7];
        #pragma unroll
        for (int n = 0; n < 7; ++n) bias_r[n] = blin[nbase + n * 16 + lrow];

        f32x4 acc[4][7];
        #pragma unroll
        for (int m = 0; m < 4; ++m)
            #pragma unroll
            for (int n = 0; n < 7; ++n)
                acc[m][n] = (f32x4){0.f, 0.f, 0.f, 0.f};

        const char* aBase = (const char*)sA + (wv * 64 + lrow) * (KP * 2) + lko;
        const char* bBase = (const char*)sW + lrow * (KP * 2) + lko;

        // 6 full K-steps (k = 0..191)
        #pragma unroll
        for (int kk = 0; kk < 6; ++kk) {
            s16x8 a[4], b[7];
            #pragma unroll
            for (int m = 0; m < 4; ++m)
                a[m] = *(const s16x8*)(aBase + m * 16 * (KP * 2) + kk * 64);
            #pragma unroll
            for (int n = 0; n < 7; ++n)
                b[n] = *(const s16x8*)(bBase + n * 16 * (KP * 2) + kk * 64);
            #pragma unroll
            for (int m = 0; m < 4; ++m)
                #pragma unroll
                for (int n = 0; n < 7; ++n)
                    acc[m][n] = __builtin_amdgcn_mfma_f32_16x16x32_bf16(
                        a[m], b[n], acc[m][n], 0, 0, 0);
        }

        // K tail: k = 192..195 real + 196..199 zeros; lanes with l>=16 masked to 0
        {
            const bool sel = ((l >> 4) == 0);
            const int toff = sel ? 384 : 0;   // byte offset of k=192 slice (or safe addr)
            const s16x8 zero8 = {0, 0, 0, 0, 0, 0, 0, 0};
            s16x8 a[4], b[7];
            #pragma unroll
            for (int m = 0; m < 4; ++m) {
                s16x8 t = *(const s16x8*)((const char*)sA +
                           (wv * 64 + m * 16 + lrow) * (KP * 2) + toff);
                a[m] = sel ? t : zero8;
            }
            #pragma unroll
            for (int n = 0; n < 7; ++n) {
                s16x8 t = *(const s16x8*)((const char*)sW +
                           (n * 16 + lrow) * (KP * 2) + toff);
                b[n] = sel ? t : zero8;
            }
            #pragma unroll
            for (int m = 0; m < 4; ++m)
                #pragma unroll
                for (int n = 0; n < 7; ++n)
                    acc[m][n] = __builtin_amdgcn_mfma_f32_16x16x32_bf16(
                        a[m], b[n], acc[m][n], 0, 0, 0);
        }

        // ---------------- store: each 16-lane group writes one aligned 64B line ----
        const int rgrp = (l >> 4) * 4;
        #pragma unroll
        for (int m = 0; m < 4; ++m) {
            size_t row0 = outRowBase + (size_t)(wv * 64 + m * 16 + rgrp);
            #pragma unroll
            for (int n = 0; n < 7; ++n) {
                int col = nbase + n * 16 + lrow;
                #pragma unroll
                for (int j = 0; j < 4; ++j) {
                    out[(row0 + j) * 784 + col] = acc[m][n][j] + bias_r[n];
                }
            }
        }
    }
}

extern "C" void kernel_launch(void* const* d_in, const int* in_sizes, int n_in,
                              void* d_out, int out_size, void* d_ws, size_t ws_size,
                              hipStream_t stream) {
    const float* x    = (const float*)d_in[0];   // [32768,1,28,28]
    const float* Wlin = (const float*)d_in[1];   // [784,196]
    const float* blin = (const float*)d_in[2];   // [784]
    float* out = (float*)d_out;                  // [32768,4,784]

    const int M = 32768 * 4;                     // 131072 rows
    dim3 grid(M / BM);                           // 512 blocks
    dim3 block(256);
    patch_linear_mfma<<<grid, block, 0, stream>>>(x, Wlin, blin, out);
}

// Round 2
// 246.750 us; speedup vs baseline: 1.1002x; 1.1002x over previous
//
#include <hip/hip_runtime.h>

#define BM 128          // rows per block = 32 images x 4 patches
#define BN 112          // output cols per chunk (7 chunks of 112 = 784)
#define KP 200          // sA row stride in bf16 elements (196 real + 4 zero pad)
#define KW 224          // W padded K (bf16), stride 448 B
#define NCH 7

typedef float f32x4 __attribute__((ext_vector_type(4)));
typedef short s16x8 __attribute__((ext_vector_type(8)));

// bf16 copy of Wlin, zero-padded K 196->224, row-major [784][224]
__device__ unsigned short g_Wb[784 * KW];

__device__ __forceinline__ unsigned short f2bf(float f) {
    unsigned int u = __builtin_bit_cast(unsigned int, f);
    u += 0x7fffu + ((u >> 16) & 1u);          // round-to-nearest-even
    return (unsigned short)(u >> 16);
}

__global__ void prep_w(const float* __restrict__ W) {
    int t = blockIdx.x * 256 + threadIdx.x;   // 784 * 56 threads, 4 k each
    if (t >= 784 * 56) return;
    int col = t / 56;
    int k   = (t - col * 56) * 4;
    uint2 pk;
    if (k < 196) {
        f32x4 d = *(const f32x4*)(W + col * 196 + k);   // 16B aligned: (196c+k)%4==0
        pk.x = (unsigned int)f2bf(d[0]) | ((unsigned int)f2bf(d[1]) << 16);
        pk.y = (unsigned int)f2bf(d[2]) | ((unsigned int)f2bf(d[3]) << 16);
    } else {
        pk.x = 0u; pk.y = 0u;
    }
    *(uint2*)(g_Wb + col * KW + k) = pk;
}

__global__ __launch_bounds__(512, 4)
void patch_linear_mfma(const float* __restrict__ x,
                       const float* __restrict__ blin,
                       float* __restrict__ out) {
    __shared__ __align__(16) short sA[BM * KP];   // 51.2 KB

    const int tid  = threadIdx.x;
    const int l    = tid & 63;
    const int wv   = tid >> 6;          // wave 0..7 -> m-frag (16 rows each)
    const int lrow = l & 15;
    const int lko  = (l >> 4) * 16;     // byte offset of this lane's k-slice

    // ---------------- stage A once: 32 images -> patch-layout bf16 ----------------
    const float* xb = x + (size_t)blockIdx.x * (BM / 4) * 784;
    const f32x4* xv = (const f32x4*)xb;
    for (int v = tid; v < (BM / 4) * 784 / 4; v += 512) {   // 6272 vectors
        f32x4 d = xv[v];
        int F   = v * 4;
        int img = F / 784;
        int rem = F - img * 784;
        int h   = rem / 28;
        int w0  = rem - h * 28;          // in {0,4,...,24}
        int ph  = h / 14;
        int r   = h - ph * 14;
        int rowb = img * 4 + ph * 2;
        #pragma unroll
        for (int p = 0; p < 2; ++p) {
            int w  = w0 + 2 * p;         // even => a bf16 pair never straddles a patch
            int pw = (w >= 14) ? 1 : 0;
            int c  = w - pw * 14;
            int row = rowb + pw;
            unsigned int pack = (unsigned int)f2bf(d[2 * p]) |
                                ((unsigned int)f2bf(d[2 * p + 1]) << 16);
            *(unsigned int*)((char*)sA + row * (KP * 2) + (r * 14 + c) * 2) = pack;
        }
    }
    if (tid < BM) {   // zero pad k = 196..199
        *(unsigned long long*)((char*)sA + tid * (KP * 2) + 392) = 0ull;
    }
    __syncthreads();   // the ONLY barrier in the kernel

    const size_t outRowBase = (size_t)blockIdx.x * BM;
    const char*  aBase = (const char*)sA + (wv * 16 + lrow) * (KP * 2) + lko;
    const char*  wBytes = (const char*)g_Wb;
    const int    bLane = lrow * (KW * 2) + lko;   // per-lane byte offset into a W row group

    for (int ch = 0; ch < NCH; ++ch) {
        const int nbase = ch * BN;
        const char* wChunk = wBytes + (size_t)nbase * (KW * 2) + bLane;

        float bias_r[7];
        #pragma unroll
        for (int n = 0; n < 7; ++n) bias_r[n] = blin[nbase + n * 16 + lrow];

        f32x4 acc[7];
        #pragma unroll
        for (int n = 0; n < 7; ++n) acc[n] = (f32x4){0.f, 0.f, 0.f, 0.f};

        // 6 full K-steps (k = 0..191)
        #pragma unroll
        for (int kk = 0; kk < 6; ++kk) {
            s16x8 a = *(const s16x8*)(aBase + kk * 64);
            s16x8 b[7];
            #pragma unroll
            for (int n = 0; n < 7; ++n)
                b[n] = *(const s16x8*)(wChunk + n * 16 * (KW * 2) + kk * 64);
            #pragma unroll
            for (int n = 0; n < 7; ++n)
                acc[n] = __builtin_amdgcn_mfma_f32_16x16x32_bf16(a, b[n], acc[n], 0, 0, 0);
        }

        // K tail (k=192..223): W is truly zero-padded; mask A for lanes l>=16
        {
            const bool sel  = ((l >> 4) == 0);
            const int  toff = sel ? 384 : 0;   // k=192 slice (or safe in-row addr)
            const s16x8 zero8 = {0, 0, 0, 0, 0, 0, 0, 0};
            s16x8 t = *(const s16x8*)((const char*)sA +
                        (wv * 16 + lrow) * (KP * 2) + toff);
            s16x8 a = sel ? t : zero8;
            s16x8 b[7];
            #pragma unroll
            for (int n = 0; n < 7; ++n)
                b[n] = *(const s16x8*)(wChunk + n * 16 * (KW * 2) + 6 * 64);
            #pragma unroll
            for (int n = 0; n < 7; ++n)
                acc[n] = __builtin_amdgcn_mfma_f32_16x16x32_bf16(a, b[n], acc[n], 0, 0, 0);
        }

        // store: each 16-lane group writes one aligned 64B line per (n,j)
        const int rgrp = (l >> 4) * 4;
        size_t row0 = outRowBase + (size_t)(wv * 16 + rgrp);
        #pragma unroll
        for (int n = 0; n < 7; ++n) {
            int col = nbase + n * 16 + lrow;
            #pragma unroll
            for (int j = 0; j < 4; ++j) {
                out[(row0 + j) * 784 + col] = acc[n][j] + bias_r[n];
            }
        }
    }
}

extern "C" void kernel_launch(void* const* d_in, const int* in_sizes, int n_in,
                              void* d_out, int out_size, void* d_ws, size_t ws_size,
                              hipStream_t stream) {
    const float* x    = (const float*)d_in[0];   // [32768,1,28,28]
    const float* Wlin = (const float*)d_in[1];   // [784,196]
    const float* blin = (const float*)d_in[2];   // [784]
    float* out = (float*)d_out;                  // [32768,4,784]

    prep_w<<<(784 * 56 + 255) / 256, 256, 0, stream>>>(Wlin);

    const int M = 32768 * 4;                     // 131072 rows
    dim3 grid(M / BM);                           // 1024 blocks
    dim3 block(512);
    patch_linear_mfma<<<grid, block, 0, stream>>>(x, blin, out);
}